// Round 1
// baseline (256.171 us; speedup 1.0000x reference)
//
#include <hip/hip_runtime.h>

#define B 1024
#define F 256
#define D 64

// ---------------------------------------------------------------------------
// Workspace layout (floats):
//   trans : 2*F*D   @ 0        (QK transforms of indicator)
//   qkv   : 3*F*D   @ 32768
//   Mt    : F*F     @ 81920    Mt[j*F+i] = gate[i][j] * cross[i][j]
//   s0    : B*F     @ 147456
//   s1    : B*F     @ 409600
//   s2    : B*F     @ 671744
// total = 933888 floats = 3.74 MB
// ---------------------------------------------------------------------------

// Kernel A: trans[n,f,e] = sum_d indicator[f,d]*W_qk[n,d,e]  (n=0,1)
//           qkv[m,f,e]   = sum_d indicator[f,d]*W_qkv[m,d,e] (m=0,1,2)
__global__ void precompute_trans(const float* __restrict__ indicator,
                                 const float* __restrict__ W_qk,
                                 const float* __restrict__ W_qkv,
                                 float* __restrict__ trans,
                                 float* __restrict__ qkv) {
    int idx = blockIdx.x * blockDim.x + threadIdx.x;   // 0 .. 5*F*D
    int n   = idx / (F * D);
    int rem = idx - n * (F * D);
    int f   = rem / D;
    int e   = rem - f * D;
    const float* W = (n < 2) ? (W_qk + n * D * D) : (W_qkv + (n - 2) * D * D);
    const float* ind = indicator + f * D;
    float acc = 0.f;
#pragma unroll 8
    for (int d = 0; d < D; ++d) acc += ind[d] * W[d * D + e];
    if (n < 2) trans[n * F * D + f * D + e] = acc;
    else       qkv[(n - 2) * F * D + f * D + e] = acc;
}

// Kernel B: Mt[j*F+i] = (trans0[i].trans1[j] > 0) ? (qkv1[i].qkv0[j]) : 0
// (scale > 0, so gate_logits>0 <=> raw dot>0)
__global__ void compute_Mt(const float* __restrict__ trans,
                           const float* __restrict__ qkv,
                           float* __restrict__ Mt) {
    int j = blockIdx.x;    // F blocks
    int i = threadIdx.x;   // F threads
    const float* t0 = trans + i * D;
    const float* t1 = trans + F * D + j * D;
    const float* q1 = qkv + F * D + i * D;
    const float* q0 = qkv + j * D;
    float d0 = 0.f, d1 = 0.f;
#pragma unroll 8
    for (int d = 0; d < D; ++d) {
        d0 += t0[d] * t1[d];
        d1 += q1[d] * q0[d];
    }
    Mt[j * F + i] = (d0 > 0.f) ? d1 : 0.f;
}

// Kernel C: s[n][b*F+f] = feature[b,f,:] . qkv[n,f,:]
__global__ void compute_s(const float* __restrict__ feature,
                          const float* __restrict__ qkv,
                          float* __restrict__ s0,
                          float* __restrict__ s1,
                          float* __restrict__ s2) {
    int idx = blockIdx.x * blockDim.x + threadIdx.x;  // b*F + f
    int f = idx & (F - 1);
    const float4* frow = (const float4*)(feature + (size_t)idx * D);
    const float4* q0 = (const float4*)(qkv + f * D);
    const float4* q1 = (const float4*)(qkv + F * D + f * D);
    const float4* q2 = (const float4*)(qkv + 2 * F * D + f * D);
    float a0 = 0.f, a1 = 0.f, a2 = 0.f;
#pragma unroll
    for (int k = 0; k < D / 4; ++k) {
        float4 v = frow[k];
        float4 x0 = q0[k];
        float4 x1 = q1[k];
        float4 x2 = q2[k];
        a0 += v.x * x0.x + v.y * x0.y + v.z * x0.z + v.w * x0.w;
        a1 += v.x * x1.x + v.y * x1.y + v.z * x1.z + v.w * x1.w;
        a2 += v.x * x2.x + v.y * x2.y + v.z * x2.z + v.w * x2.w;
    }
    s0[idx] = a0;
    s1[idx] = a1;
    s2[idx] = a2;
}

// Kernel D: out[b,i,d] = s0[b,i]*s2[b,i] * sum_j Mt[j,i] * (s1[b,j]*qkv2[j,d])
// One block per b. 256 threads; thread tile 8(i) x 8(d); 32 i-groups x 8 d-groups.
#define TJ 8
__global__ __launch_bounds__(256) void main_gemm(const float* __restrict__ Mt,
                                                 const float* __restrict__ qkv2,
                                                 const float* __restrict__ s0,
                                                 const float* __restrict__ s1,
                                                 const float* __restrict__ s2,
                                                 float* __restrict__ out) {
    int b = blockIdx.x;
    int tid = threadIdx.x;
    int dg = tid & 7;   // d-group: 8 groups of 8 dims
    int ig = tid >> 3;  // i-group: 32 groups of 8 rows

    __shared__ float s1s[F];
    __shared__ float Mts[TJ][F];
    __shared__ float Q2s[TJ][D];

    s1s[tid] = s1[b * F + tid];

    float acc[8][8];
#pragma unroll
    for (int a = 0; a < 8; ++a)
#pragma unroll
        for (int c = 0; c < 8; ++c) acc[a][c] = 0.f;

    for (int jt = 0; jt < F; jt += TJ) {
        __syncthreads();
        // stage Mt tile: TJ*F = 2048 floats, coalesced float4
        {
            const float4* src = (const float4*)(Mt + jt * F);
            float4* dst = (float4*)(&Mts[0][0]);
            dst[tid] = src[tid];
            dst[tid + 256] = src[tid + 256];
        }
        // stage Q2 tile scaled by s1: TJ*D = 512 floats = 128 float4
        if (tid < 128) {
            int r = tid >> 4;   // tile row 0..7
            int c = tid & 15;   // float4 col 0..15
            float sc = s1s[jt + r];
            float4 q = ((const float4*)(qkv2 + (jt + r) * D))[c];
            float4 o;
            o.x = q.x * sc; o.y = q.y * sc; o.z = q.z * sc; o.w = q.w * sc;
            ((float4*)(&Q2s[0][0]))[tid] = o;
        }
        __syncthreads();
#pragma unroll
        for (int jj = 0; jj < TJ; ++jj) {
            float4 w0 = ((const float4*)(&Mts[jj][ig * 8]))[0];
            float4 w1 = ((const float4*)(&Mts[jj][ig * 8]))[1];
            float4 v0 = ((const float4*)(&Q2s[jj][dg * 8]))[0];
            float4 v1 = ((const float4*)(&Q2s[jj][dg * 8]))[1];
            float w[8] = {w0.x, w0.y, w0.z, w0.w, w1.x, w1.y, w1.z, w1.w};
            float q[8] = {v0.x, v0.y, v0.z, v0.w, v1.x, v1.y, v1.z, v1.w};
#pragma unroll
            for (int a = 0; a < 8; ++a)
#pragma unroll
                for (int c = 0; c < 8; ++c) acc[a][c] += w[a] * q[c];
        }
    }

    // epilogue: scale by g = s0*s2, store
    int ibase = ig * 8, dbase = dg * 8;
#pragma unroll
    for (int a = 0; a < 8; ++a) {
        int i = ibase + a;
        float g = s0[b * F + i] * s2[b * F + i];
        float4 o0, o1;
        o0.x = g * acc[a][0]; o0.y = g * acc[a][1];
        o0.z = g * acc[a][2]; o0.w = g * acc[a][3];
        o1.x = g * acc[a][4]; o1.y = g * acc[a][5];
        o1.z = g * acc[a][6]; o1.w = g * acc[a][7];
        float* orow = out + ((size_t)(b * F + i)) * D + dbase;
        ((float4*)orow)[0] = o0;
        ((float4*)orow)[1] = o1;
    }
}

extern "C" void kernel_launch(void* const* d_in, const int* in_sizes, int n_in,
                              void* d_out, int out_size, void* d_ws, size_t ws_size,
                              hipStream_t stream) {
    const float* feature   = (const float*)d_in[0];
    const float* indicator = (const float*)d_in[1];
    const float* W_qk      = (const float*)d_in[2];
    const float* W_qkv     = (const float*)d_in[3];
    float* out = (float*)d_out;

    float* ws    = (float*)d_ws;
    float* trans = ws;                  // 2*F*D
    float* qkv   = trans + 2 * F * D;   // 3*F*D
    float* Mt    = qkv + 3 * F * D;     // F*F
    float* s0    = Mt + F * F;          // B*F
    float* s1    = s0 + B * F;          // B*F
    float* s2    = s1 + B * F;          // B*F

    hipLaunchKernelGGL(precompute_trans, dim3((5 * F * D) / 256), dim3(256), 0,
                       stream, indicator, W_qk, W_qkv, trans, qkv);
    hipLaunchKernelGGL(compute_Mt, dim3(F), dim3(F), 0, stream, trans, qkv, Mt);
    hipLaunchKernelGGL(compute_s, dim3((B * F) / 256), dim3(256), 0, stream,
                       feature, qkv, s0, s1, s2);
    hipLaunchKernelGGL(main_gemm, dim3(B), dim3(256), 0, stream, Mt,
                       qkv + 2 * F * D, s0, s1, s2, out);
}

// Round 2
// 147.859 us; speedup vs baseline: 1.7325x; 1.7325x over previous
//
#include <hip/hip_runtime.h>
#include <stdint.h>

#define B 1024
#define F 256
#define D 64

typedef __attribute__((ext_vector_type(8))) short short8;
typedef __attribute__((ext_vector_type(4))) float f32x4;

typedef __attribute__((address_space(1))) const unsigned GU;
typedef __attribute__((address_space(3))) unsigned LU;

__device__ __forceinline__ short f2bf(float f) {
    unsigned u = __builtin_bit_cast(unsigned, f);
    u += 0x7fff + ((u >> 16) & 1);   // RNE
    return (short)(u >> 16);
}
__device__ __forceinline__ float bf2f(short s) {
    unsigned u = ((unsigned)(unsigned short)s) << 16;
    return __builtin_bit_cast(float, u);
}

// ---------------------------------------------------------------------------
// Workspace (bytes from base):
//   trans  : 2*F*D fp32
//   qkv    : 3*F*D fp32
//   s0,s1,s2 : B*F fp32 each
//   At     : [F/32][F][32] bf16  (gate*cross, K-tiled)
//   q2T    : [D][F] bf16         (qkv2 transposed)
// ---------------------------------------------------------------------------

// Kernel A: trans/qkv = indicator @ W  (5 small D x D GEMVs per f)
__global__ void precompute_trans(const float* __restrict__ indicator,
                                 const float* __restrict__ W_qk,
                                 const float* __restrict__ W_qkv,
                                 float* __restrict__ trans,
                                 float* __restrict__ qkv) {
    int idx = blockIdx.x * blockDim.x + threadIdx.x;   // 0 .. 5*F*D
    int n   = idx / (F * D);
    int rem = idx - n * (F * D);
    int f   = rem / D;
    int e   = rem - f * D;
    const float* W = (n < 2) ? (W_qk + n * D * D) : (W_qkv + (n - 2) * D * D);
    const float* ind = indicator + f * D;
    float acc = 0.f;
#pragma unroll 8
    for (int d = 0; d < D; ++d) acc += ind[d] * W[d * D + e];
    if (n < 2) trans[n * F * D + f * D + e] = acc;
    else       qkv[(n - 2) * F * D + f * D + e] = acc;
}

// Kernel B: At[(j>>5)][i][j&31] = bf16( (trans0[i].trans1[j] > 0) ? qkv1[i].qkv0[j] : 0 )
//           q2T[d][i] = bf16( qkv2[i][d] )   (folded in for j < 64)
__global__ void compute_Mt(const float* __restrict__ trans,
                           const float* __restrict__ qkv,
                           short* __restrict__ At,
                           short* __restrict__ q2T) {
    int j = blockIdx.x;    // F blocks
    int i = threadIdx.x;   // F threads
    const float* t0 = trans + i * D;
    const float* t1 = trans + F * D + j * D;
    const float* q1 = qkv + F * D + i * D;
    const float* q0 = qkv + j * D;
    float d0 = 0.f, d1 = 0.f;
#pragma unroll 8
    for (int d = 0; d < D; ++d) {
        d0 += t0[d] * t1[d];
        d1 += q1[d] * q0[d];
    }
    float v = (d0 > 0.f) ? d1 : 0.f;
    At[((j >> 5) * F + i) * 32 + (j & 31)] = f2bf(v);
    if (j < D) q2T[j * F + i] = f2bf(qkv[2 * F * D + i * D + j]);
}

// Kernel C: s[n][b*F+f] = feature[b,f,:] . qkv[n,f,:]
// 16 lanes per row, coalesced float4 loads, shfl_xor reduce.
__global__ __launch_bounds__(256) void compute_s(const float* __restrict__ feature,
                                                 const float* __restrict__ qkv,
                                                 float* __restrict__ s0,
                                                 float* __restrict__ s1,
                                                 float* __restrict__ s2) {
    int g   = blockIdx.x * 256 + threadIdx.x;
    int row = g >> 4;          // b*F + f
    int l   = g & 15;
    int f   = row & (F - 1);
    float4 fv = ((const float4*)(feature + (size_t)row * D))[l];
    float4 q0 = ((const float4*)(qkv + f * D))[l];
    float4 q1 = ((const float4*)(qkv + F * D + f * D))[l];
    float4 q2 = ((const float4*)(qkv + 2 * F * D + f * D))[l];
    float p0 = fv.x * q0.x + fv.y * q0.y + fv.z * q0.z + fv.w * q0.w;
    float p1 = fv.x * q1.x + fv.y * q1.y + fv.z * q1.z + fv.w * q1.w;
    float p2 = fv.x * q2.x + fv.y * q2.y + fv.z * q2.z + fv.w * q2.w;
#pragma unroll
    for (int m = 1; m < 16; m <<= 1) {
        p0 += __shfl_xor(p0, m, 64);
        p1 += __shfl_xor(p1, m, 64);
        p2 += __shfl_xor(p2, m, 64);
    }
    if (l == 0) {
        s0[row] = p0;
        s1[row] = p1;
        s2[row] = p2;
    }
}

// Kernel D (MFMA): per block, C[128 i][128 n] = A[128 i][256 j] @ Bm[256 j][128 n]
//   n = bl*64 + d, batches (b0, b0+1); Bm[j][n] = s1[b0+bl][j] * qkv2[j][d]
//   out[b, i, d] = s0[b,i]*s2[b,i] * C
__global__ __launch_bounds__(256) void main_mfma(const short* __restrict__ At,
                                                 const short* __restrict__ q2T,
                                                 const float* __restrict__ s0,
                                                 const float* __restrict__ s1,
                                                 const float* __restrict__ s2,
                                                 float* __restrict__ out) {
    int blk = blockIdx.x;
    int ih  = blk & 1;        // i-half
    int bp  = blk >> 1;       // batch pair
    int b0  = bp * 2;
    int i0  = ih * 128;

    __shared__ short As[128 * 32];   // [i_local][j_local] bf16, 8 KB
    __shared__ short Bs[128 * 32];   // [n][j_local] bf16, 8 KB
    __shared__ float s1s[2 * F];     // s1 for both batches
    __shared__ float gs[2 * 128];    // g = s0*s2 for both batches, i-half rows

    int tid = threadIdx.x;

    // stage s1 and g
    s1s[tid]       = s1[b0 * F + tid];
    s1s[F + tid]   = s1[(b0 + 1) * F + tid];
    {
        int bl = tid >> 7, il = tid & 127;
        int r  = (b0 + bl) * F + i0 + il;
        gs[tid] = s0[r] * s2[r];
    }

    int wave = tid >> 6;
    int lane = tid & 63;
    int wr = wave >> 1, wc = wave & 1;   // wave's 64x64 quadrant
    int l16 = lane & 15;
    int lq  = lane >> 4;                 // 0..3

    f32x4 acc[4][4];
#pragma unroll
    for (int mt = 0; mt < 4; ++mt)
#pragma unroll
        for (int nt = 0; nt < 4; ++nt) acc[mt][nt] = (f32x4){0.f, 0.f, 0.f, 0.f};

    for (int jt = 0; jt < F / 32; ++jt) {
        __syncthreads();
        // --- stage A tile (8 KB contiguous) via global_load_lds width=16 ---
        {
            const char* gA = (const char*)(At + ((size_t)jt * F + i0) * 32);
            __builtin_amdgcn_global_load_lds((GU*)(gA + tid * 16),
                                             (LU*)((char*)As + tid * 16), 16, 0, 0);
            __builtin_amdgcn_global_load_lds((GU*)(gA + 4096 + tid * 16),
                                             (LU*)((char*)As + 4096 + tid * 16), 16, 0, 0);
        }
        // --- stage B tile: Bs[n][jl] = s1[b(n)][jt*32+jl] * q2T[d(n)][jt*32+jl] ---
        {
            int n  = tid & 127;
            int jh = tid >> 7;           // which 16-element half of the 32-row
            int d  = n & 63, bl = n >> 6;
            const short* q  = q2T + d * F + jt * 32 + jh * 16;
            const float* sv = s1s + bl * F + jt * 32 + jh * 16;
            short* bd = Bs + n * 32 + jh * 16;
#pragma unroll
            for (int k = 0; k < 16; ++k) bd[k] = f2bf(bf2f(q[k]) * sv[k]);
        }
        __syncthreads();
        // --- fragments + MFMA ---
        short8 af[4], bf[4];
        const short* aBase = As + ((wr * 64 + l16) * 32) + lq * 8;
        const short* bBase = Bs + ((wc * 64 + l16) * 32) + lq * 8;
#pragma unroll
        for (int mt = 0; mt < 4; ++mt) af[mt] = *(const short8*)(aBase + mt * 16 * 32);
#pragma unroll
        for (int nt = 0; nt < 4; ++nt) bf[nt] = *(const short8*)(bBase + nt * 16 * 32);
#pragma unroll
        for (int mt = 0; mt < 4; ++mt)
#pragma unroll
            for (int nt = 0; nt < 4; ++nt)
                acc[mt][nt] = __builtin_amdgcn_mfma_f32_16x16x32_bf16(
                    af[mt], bf[nt], acc[mt][nt], 0, 0, 0);
    }

    // --- epilogue: out[b, i, d] = g * acc; wave column-half == batch ---
    int b = b0 + wc;
#pragma unroll
    for (int mt = 0; mt < 4; ++mt) {
#pragma unroll
        for (int r = 0; r < 4; ++r) {
            int i_loc = wr * 64 + mt * 16 + lq * 4 + r;
            float g = gs[wc * 128 + i_loc];
            float* orow = out + ((size_t)(b * F + i0 + i_loc)) * D;
#pragma unroll
            for (int nt = 0; nt < 4; ++nt)
                orow[nt * 16 + l16] = g * acc[mt][nt][r];
        }
    }
}

extern "C" void kernel_launch(void* const* d_in, const int* in_sizes, int n_in,
                              void* d_out, int out_size, void* d_ws, size_t ws_size,
                              hipStream_t stream) {
    const float* feature   = (const float*)d_in[0];
    const float* indicator = (const float*)d_in[1];
    const float* W_qk      = (const float*)d_in[2];
    const float* W_qkv     = (const float*)d_in[3];
    float* out = (float*)d_out;

    float* ws    = (float*)d_ws;
    float* trans = ws;                    // 2*F*D fp32
    float* qkv   = trans + 2 * F * D;     // 3*F*D fp32
    float* s0    = qkv + 3 * F * D;       // B*F fp32
    float* s1    = s0 + B * F;
    float* s2    = s1 + B * F;
    short* At    = (short*)(s2 + B * F);  // F*F bf16, K-tiled
    short* q2T   = At + F * F;            // D*F bf16

    hipLaunchKernelGGL(precompute_trans, dim3((5 * F * D) / 256), dim3(256), 0,
                       stream, indicator, W_qk, W_qkv, trans, qkv);
    hipLaunchKernelGGL(compute_Mt, dim3(F), dim3(F), 0, stream, trans, qkv, At, q2T);
    hipLaunchKernelGGL(compute_s, dim3(B * F * 16 / 256), dim3(256), 0, stream,
                       feature, qkv, s0, s1, s2);
    hipLaunchKernelGGL(main_mfma, dim3(B), dim3(256), 0, stream, At, q2T,
                       s0, s1, s2, out);
}